// Round 4
// baseline (486.951 us; speedup 1.0000x reference)
//
#include <hip/hip_runtime.h>

typedef short bf16x8 __attribute__((ext_vector_type(8)));
typedef float f32x4 __attribute__((ext_vector_type(4)));

__device__ __forceinline__ float b2f(unsigned short u) {
  union { unsigned int i; float f; } v; v.i = ((unsigned int)u) << 16; return v.f;
}
__device__ __forceinline__ unsigned short f2b(float f) {
  unsigned int u = __float_as_uint(f);
  u += 0x7fffu + ((u >> 16) & 1u);
  return (unsigned short)(u >> 16);
}
__device__ __forceinline__ float silu_f(float s) { return s / (1.0f + __expf(-s)); }

// split fp32 -> (hi, lo) bf16
__device__ __forceinline__ void split2(float f, unsigned short& h, unsigned short& l) {
  h = f2b(f);
  l = f2b(f - b2f(h));
}

// async 16B/lane global->LDS. LDS dest = wave-uniform base + lane*16 (linear).
__device__ __forceinline__ void gload16(const unsigned short* g, unsigned short* l) {
  __builtin_amdgcn_global_load_lds(
      (const __attribute__((address_space(1))) unsigned int*)g,
      (__attribute__((address_space(3))) unsigned int*)l, 16, 0, 0);
}

// unpack 8 packed (hi | lo<<16) u32 -> hi/lo bf16x8 via v_perm (2 ops per pair)
__device__ __forceinline__ void unpack8(const unsigned* p, bf16x8& hi, bf16x8& lo) {
  uint4 a = *(const uint4*)p;
  uint4 b = *(const uint4*)(p + 4);
  unsigned u[8] = {a.x, a.y, a.z, a.w, b.x, b.y, b.z, b.w};
  unsigned hw[4], lw[4];
  #pragma unroll
  for (int j = 0; j < 4; j++) {
    hw[j] = __builtin_amdgcn_perm(u[2 * j + 1], u[2 * j], 0x05040100u);
    lw[j] = __builtin_amdgcn_perm(u[2 * j + 1], u[2 * j], 0x07060302u);
  }
  hi = *(bf16x8*)hw;
  lo = *(bf16x8*)lw;
}

// K0: split W fp32 -> Wh/Wl bf16 planes [768][256], once.
__global__ __launch_bounds__(256) void k_wsplit(
    const float* __restrict__ W, unsigned short* __restrict__ Wh,
    unsigned short* __restrict__ Wl) {
  int e = (blockIdx.x * 256 + threadIdx.x) * 8;  // 96 blocks * 256 * 8 = 768*256
  float4 a = *(const float4*)(W + e);
  float4 b = *(const float4*)(W + e + 4);
  float v[8] = {a.x, a.y, a.z, a.w, b.x, b.y, b.z, b.w};
  unsigned short h[8], l[8];
  #pragma unroll
  for (int j = 0; j < 8; j++) split2(v[j], h[j], l[j]);
  uint4 ph, pl;
  ph.x = h[0] | ((unsigned)h[1] << 16); ph.y = h[2] | ((unsigned)h[3] << 16);
  ph.z = h[4] | ((unsigned)h[5] << 16); ph.w = h[6] | ((unsigned)h[7] << 16);
  pl.x = l[0] | ((unsigned)l[1] << 16); pl.y = l[2] | ((unsigned)l[3] << 16);
  pl.z = l[4] | ((unsigned)l[5] << 16); pl.w = l[6] | ((unsigned)l[7] << 16);
  *(uint4*)(Wh + e) = ph;
  *(uint4*)(Wl + e) = pl;
}

// K1: T = silu(x + pab) + pqb, written TRANSPOSED as split planes into out[:,256:512]:
//   per batch: Th u16[4096][256] then Tl u16[4096][256] (2MB + 2MB = exactly the region).
__global__ __launch_bounds__(256) void k_prep(
    const float* __restrict__ x, const float* __restrict__ pab,
    const float* __restrict__ pqb, float* __restrict__ out) {
  __shared__ unsigned short th[64 * 64], tl[64 * 64];  // [n][c], sub-chunk swizzled
  int blk = blockIdx.x;
  int nb = blk & 63;
  int cb = (blk >> 6) & 3;
  int b = blk >> 8;
  int n0 = nb * 64, c0 = cb * 64;
  int t = threadIdx.x;
  int nn = (t & 15) * 4;
  #pragma unroll
  for (int p = 0; p < 2; p++) {
    int c = 2 * (p * 16 + (t >> 4));  // even
    float pa0 = pab[c0 + c], pq0 = pqb[c0 + c];
    float pa1 = pab[c0 + c + 1], pq1 = pqb[c0 + c + 1];
    float4 x0 = *(const float4*)(x + ((long long)(b * 256 + c0 + c)) * 4096 + n0 + nn);
    float4 x1 = *(const float4*)(x + ((long long)(b * 256 + c0 + c + 1)) * 4096 + n0 + nn);
    float t0[4] = {silu_f(x0.x + pa0) + pq0, silu_f(x0.y + pa0) + pq0,
                   silu_f(x0.z + pa0) + pq0, silu_f(x0.w + pa0) + pq0};
    float t1[4] = {silu_f(x1.x + pa1) + pq1, silu_f(x1.y + pa1) + pq1,
                   silu_f(x1.z + pa1) + pq1, silu_f(x1.w + pa1) + pq1};
    #pragma unroll
    for (int j = 0; j < 4; j++) {
      int nr = nn + j;
      unsigned short h0, l0, h1, l1;
      split2(t0[j], h0, l0);
      split2(t1[j], h1, l1);
      // physical col: swizzle 8-elem sub-chunk by row (c even => pair stays in chunk)
      int pcol = ((((c >> 3) ^ (nr & 7)) << 3) | (c & 7));
      *(unsigned int*)(th + nr * 64 + pcol) = (unsigned)h0 | ((unsigned)h1 << 16);
      *(unsigned int*)(tl + nr * 64 + pcol) = (unsigned)l0 | ((unsigned)l1 << 16);
    }
  }
  __syncthreads();
  unsigned short* Th = (unsigned short*)(out + ((long long)(b * 512 + 256)) * 4096);
  unsigned short* Tl = Th + 4096 * 256;
  #pragma unroll
  for (int q = 0; q < 2; q++) {
    int s = q * 256 + t;
    int n = s >> 3, sc = s & 7;
    int psc = sc ^ (n & 7);
    uint4 vh = *(const uint4*)(th + n * 64 + psc * 8);
    uint4 vl = *(const uint4*)(tl + n * 64 + psc * 8);
    *(uint4*)(Th + (long long)(n0 + n) * 256 + c0 + sc * 8) = vh;
    *(uint4*)(Tl + (long long)(n0 + n) * 256 + c0 + sc * 8) = vl;
  }
}

// K6 (last): x_preact = silu(x + pab) fp32 -> out[:,0:256]
__global__ __launch_bounds__(256) void k_act(
    const float* __restrict__ x, const float* __restrict__ pab,
    float* __restrict__ out) {
  long long e = ((long long)blockIdx.x * 256 + threadIdx.x) * 4;
  int b = (int)(e >> 20);
  int c = ((int)(e >> 12)) & 255;
  int n = (int)(e & 4095);
  float4 xv = *(const float4*)(x + e);
  float pa = pab[c];
  float4 o = {silu_f(xv.x + pa), silu_f(xv.y + pa), silu_f(xv.z + pa), silu_f(xv.w + pa)};
  *(float4*)(out + ((long long)(b * 512 + c)) * 4096 + n) = o;
}

// K2/K4: GEMM qkv rows [o_base, o_base+obt*128). USE_LO=1 -> 3-term split-bf16.
// A (W, 0.75MB L2-resident) loaded DIRECTLY global->VGPR per step (no LDS).
// LDS holds only B (T) planes, double-buffered: 32KB (USE_LO) / 16KB -> 4 blocks/CU
// with __launch_bounds__(256,4). Counted vmcnt: prefetch stays in flight across
// barriers; A loads are older than the nI prefetch gloads so vmcnt(nI) retires them.
//   part 0 (q): +bias+PE, FiLM -> out[:,0:256] packed (hi|lo<<16) u32
//   part 1 (k): +bias+PE      -> kv packed u32
//   part 2 (v): +bias         -> kv fp32
template <int USE_LO>
__global__ __launch_bounds__(256, 4) void k_qkv(
    const unsigned short* __restrict__ Wh, const unsigned short* __restrict__ Wl,
    const float* __restrict__ qkvb,
    const float* __restrict__ peqh, const float* __restrict__ peqw,
    const float* __restrict__ pekh, const float* __restrict__ pekw,
    const float* __restrict__ modm, const float* __restrict__ modb,
    float* __restrict__ out, float* __restrict__ kv,
    int o_base, int obt) {
  extern __shared__ unsigned short sm[];
  const int BUFS = USE_LO ? 8192 : 4096;  // u16 per buffer (B planes only)

  int bx = blockIdx.x;
  int nb = bx & 31;
  int hb = bx >> 5;
  int ob = hb % obt;
  int b = hb / obt;
  int o0 = o_base + ob * 128, n0 = nb * 128;
  int t = threadIdx.x;
  int lane = t & 63, w = t >> 6;
  int wm = w >> 1, wn = w & 1;
  int l15 = lane & 15, l4 = lane >> 4;

  const unsigned short* Th =
      (const unsigned short*)(out + ((long long)(b * 512 + 256)) * 4096);
  const unsigned short* Tl = Th + 4096 * 256;

  // B staging assignment: USE_LO: waves 0,1 -> Bh; 2,3 -> Bl; 64 rows each.
  //                       else:   all waves -> Bh; 32 rows each.
  const unsigned short* src;
  int dstoff, row0;
  if (USE_LO) {
    src = (w & 2) ? Tl : Th;
    dstoff = ((w & 2) ? 4096 : 0) + (w & 1) * 2048;
    row0 = n0 + (w & 1) * 64;
  } else {
    src = Th;
    dstoff = w * 1024;
    row0 = n0 + w * 32;
  }
  const int nI = USE_LO ? 4 : 2;  // gload16 instrs per wave per K-step (1KB each)
  // source-side swizzle: lane writes LDS (row=l>>2, chunk=l&3); fetch logical
  // chunk (l&3) ^ ((l>>3)&3) so physical chunk = logical ^ ((row>>1)&3).
  int laneoff = (lane >> 2) * 256 + (((lane & 3) ^ ((lane >> 3) & 3)) << 3);
  const unsigned short* sbase = src + (long long)row0 * 256 + laneoff;

  // A-fragment per-lane global base: row = o0 + wm*64 + i*16 + l15, col = step*32 + l4*8
  const unsigned short* Ahb = Wh + (long long)(o0 + wm * 64 + l15) * 256 + l4 * 8;
  const unsigned short* Alb = Wl + (long long)(o0 + wm * 64 + l15) * 256 + l4 * 8;

  f32x4 z = {0.f, 0.f, 0.f, 0.f};
  f32x4 acc[4][4];
  #pragma unroll
  for (int i = 0; i < 4; i++)
    #pragma unroll
    for (int j = 0; j < 4; j++) acc[i][j] = z;

  // read-side physical chunk for this lane (row%16 == l15, i*16 keeps (row>>1)&3)
  int sw = (l4 ^ ((l15 >> 1) & 3)) << 3;

  // prologue: stage B(0) into buf 0 (stays in flight; counted below)
  #pragma unroll
  for (int i = 0; i < nI; i++) gload16(sbase + i * 4096, sm + dstoff + i * 512);

  int cur = 0;
  for (int step = 0; step < 8; ++step) {
    // A regs for this step (global, L2-resident W; older than the prefetch
    // gloads below, so the counted vmcnt retires them too)
    bf16x8 ah[4], al[4];
    #pragma unroll
    for (int i = 0; i < 4; i++) {
      ah[i] = *(const bf16x8*)(Ahb + i * 4096 + step * 32);
      if (USE_LO) al[i] = *(const bf16x8*)(Alb + i * 4096 + step * 32);
    }
    // issue next K-step's B prefetch; wait COUNTED vmcnt: previous B batch and
    // A loads done, just-issued batch stays in flight across barrier + MFMA.
    if (step < 7) {
      const unsigned short* sp = sbase + (step + 1) * 32;
      unsigned short* dp = sm + (cur ^ 1) * BUFS + dstoff;
      #pragma unroll
      for (int i = 0; i < nI; i++) gload16(sp + i * 4096, dp + i * 512);
      if (USE_LO) asm volatile("s_waitcnt vmcnt(4)" ::: "memory");
      else        asm volatile("s_waitcnt vmcnt(2)" ::: "memory");
    } else {
      asm volatile("s_waitcnt vmcnt(0)" ::: "memory");
    }
    __builtin_amdgcn_s_barrier();          // everyone's B tile in LDS
    __builtin_amdgcn_sched_barrier(0);     // pin ds_reads below the barrier
    unsigned short* Bh = sm + cur * BUFS;
    unsigned short* Bl = Bh + 4096;
    bf16x8 bh[4], bl[4];
    #pragma unroll
    for (int j = 0; j < 4; j++) {
      int rowB = (wn * 64 + j * 16 + l15) * 32;
      bh[j] = *(const bf16x8*)(Bh + rowB + sw);
      if (USE_LO) bl[j] = *(const bf16x8*)(Bl + rowB + sw);
    }
    #pragma unroll
    for (int i = 0; i < 4; i++)
      #pragma unroll
      for (int j = 0; j < 4; j++) {
        acc[i][j] = __builtin_amdgcn_mfma_f32_16x16x32_bf16(ah[i], bh[j], acc[i][j], 0, 0, 0);
        if (USE_LO) {
          acc[i][j] = __builtin_amdgcn_mfma_f32_16x16x32_bf16(ah[i], bl[j], acc[i][j], 0, 0, 0);
          acc[i][j] = __builtin_amdgcn_mfma_f32_16x16x32_bf16(al[i], bh[j], acc[i][j], 0, 0, 0);
        }
      }
    __builtin_amdgcn_sched_barrier(0);
    // reads of buf `cur` consumed by MFMA; bare barrier, NO vmcnt drain.
    __builtin_amdgcn_s_barrier();
    cur ^= 1;
  }

  int part = o0 >> 8;
  #pragma unroll
  for (int i = 0; i < 4; i++) {
    #pragma unroll
    for (int r = 0; r < 4; r++) {
      int o = o0 + wm * 64 + i * 16 + l4 * 4 + r;
      int cch = o & 255;
      float bias = qkvb[o];
      float mm = 0.f, mb = 0.f;
      if (part == 0) { mm = modm[b * 256 + cch]; mb = modb[b * 256 + cch]; }
      #pragma unroll
      for (int j = 0; j < 4; j++) {
        int n = n0 + wn * 64 + j * 16 + l15;
        float v = acc[i][j][r] + bias;
        int hh = n >> 6, ww = n & 63;
        if (part == 0) {
          v += peqh[cch * 64 + hh] + peqw[cch * 64 + ww];
          v = v * mm + mb;
          unsigned short h, l; split2(v, h, l);
          ((unsigned*)out)[((long long)(b * 512 + cch)) * 4096 + n] =
              (unsigned)h | ((unsigned)l << 16);
        } else if (part == 1) {
          v += pekh[cch * 64 + hh] + pekw[cch * 64 + ww];
          unsigned short h, l; split2(v, h, l);
          ((unsigned*)kv)[((long long)(b * 256 + cch)) * 4096 + n] =
              (unsigned)h | ((unsigned)l << 16);
        } else {
          kv[((long long)(b * 256 + cch)) * 4096 + n] = v;
        }
      }
    }
  }
}

// K3: logitsP[chunk][b,h,c,d] = scale * sum_{n in chunk} q[c,n] k[d,n]
// q, k read as packed split-bf16 (written by k_qkv) -> v_perm unpack, no cvt.
__global__ __launch_bounds__(256) void k_logits(
    const unsigned* __restrict__ qp, const unsigned* __restrict__ kp,
    float* __restrict__ logitsP) {
  int bx = blockIdx.x;
  int chunk = bx & 3, bh = bx >> 2;
  int b = bh >> 3, h = bh & 7;
  int t = threadIdx.x, lane = t & 63, w = t >> 6;
  int l15 = lane & 15, l4 = lane >> 4;
  const unsigned* qb = qp + ((long long)(b * 512 + h * 32)) * 4096;
  const unsigned* kb = kp + ((long long)(b * 256 + h * 32)) * 4096;
  f32x4 z = {0.f, 0.f, 0.f, 0.f};
  f32x4 acc[2][2] = {z, z, z, z};
  int nstep0 = chunk * 1024 + w * 256;
  for (int it = 0; it < 8; it++) {
    int n = nstep0 + it * 32 + l4 * 8;
    bf16x8 qh0, ql0, qh1, ql1, kh0, kl0, kh1, kl1;
    unpack8(qb + (long long)l15 * 4096 + n, qh0, ql0);
    unpack8(qb + (long long)(16 + l15) * 4096 + n, qh1, ql1);
    unpack8(kb + (long long)l15 * 4096 + n, kh0, kl0);
    unpack8(kb + (long long)(16 + l15) * 4096 + n, kh1, kl1);
    acc[0][0] = __builtin_amdgcn_mfma_f32_16x16x32_bf16(qh0, kh0, acc[0][0], 0, 0, 0);
    acc[0][0] = __builtin_amdgcn_mfma_f32_16x16x32_bf16(qh0, kl0, acc[0][0], 0, 0, 0);
    acc[0][0] = __builtin_amdgcn_mfma_f32_16x16x32_bf16(ql0, kh0, acc[0][0], 0, 0, 0);
    acc[0][1] = __builtin_amdgcn_mfma_f32_16x16x32_bf16(qh0, kh1, acc[0][1], 0, 0, 0);
    acc[0][1] = __builtin_amdgcn_mfma_f32_16x16x32_bf16(qh0, kl1, acc[0][1], 0, 0, 0);
    acc[0][1] = __builtin_amdgcn_mfma_f32_16x16x32_bf16(ql0, kh1, acc[0][1], 0, 0, 0);
    acc[1][0] = __builtin_amdgcn_mfma_f32_16x16x32_bf16(qh1, kh0, acc[1][0], 0, 0, 0);
    acc[1][0] = __builtin_amdgcn_mfma_f32_16x16x32_bf16(qh1, kl0, acc[1][0], 0, 0, 0);
    acc[1][0] = __builtin_amdgcn_mfma_f32_16x16x32_bf16(ql1, kh0, acc[1][0], 0, 0, 0);
    acc[1][1] = __builtin_amdgcn_mfma_f32_16x16x32_bf16(qh1, kh1, acc[1][1], 0, 0, 0);
    acc[1][1] = __builtin_amdgcn_mfma_f32_16x16x32_bf16(qh1, kl1, acc[1][1], 0, 0, 0);
    acc[1][1] = __builtin_amdgcn_mfma_f32_16x16x32_bf16(ql1, kh1, acc[1][1], 0, 0, 0);
  }
  __shared__ float red[4][1024];
  #pragma unroll
  for (int ch = 0; ch < 2; ch++)
    #pragma unroll
    for (int dh = 0; dh < 2; dh++)
      #pragma unroll
      for (int r = 0; r < 4; r++) {
        int crow = ch * 16 + l4 * 4 + r;
        int dcol = dh * 16 + l15;
        red[w][crow * 32 + dcol] = acc[ch][dh][r];
      }
  __syncthreads();
  const float scale = 0.1767766952966369f;  // 1/sqrt(32)
  #pragma unroll
  for (int i = 0; i < 4; i++) {
    int idx = i * 256 + t;
    float s = (red[0][idx] + red[1][idx] + red[2][idx] + red[3][idx]) * scale;
    logitsP[(long long)chunk * 131072 + bh * 1024 + idx] = s;
  }
}

// K5: softmax (sum 4 partials) + out = weights @ v -> out[:,256:512] fp32
__global__ __launch_bounds__(256) void k_pv(
    const float* __restrict__ kv,    // v
    const float* __restrict__ logitsP,
    float* __restrict__ out) {
  int bx = blockIdx.x;
  int ntile = bx & 15, bh = bx >> 4;
  int b = bh >> 3, h = bh & 7;
  int t = threadIdx.x;
  __shared__ float raw[32][33];   // [c][d], padded: serial reads conflict-free
  __shared__ float wsm[32][33];
  #pragma unroll
  for (int i = 0; i < 4; i++) {
    int idx = i * 256 + t;
    float s = logitsP[bh * 1024 + idx] + logitsP[131072 + bh * 1024 + idx]
            + logitsP[262144 + bh * 1024 + idx] + logitsP[393216 + bh * 1024 + idx];
    raw[idx >> 5][idx & 31] = s;
  }
  __syncthreads();
  if (t < 32) {
    float mx = -1e30f;
    for (int d = 0; d < 32; d++) mx = fmaxf(mx, raw[t][d]);
    float e[32]; float s = 0.f;
    for (int d = 0; d < 32; d++) { e[d] = __expf(raw[t][d] - mx); s += e[d]; }
    float inv = 1.0f / s;
    for (int d = 0; d < 32; d++) wsm[t][d] = e[d] * inv;
  }
  __syncthreads();
  int rg = t >> 6;          // wave-uniform -> wsm broadcast
  int nl = (t & 63) * 4;
  int n0 = ntile * 256 + nl;
  const float* vb = kv + ((long long)(b * 256 + h * 32)) * 4096 + n0;
  float acc[8][4];
  #pragma unroll
  for (int r = 0; r < 8; r++)
    #pragma unroll
    for (int i = 0; i < 4; i++) acc[r][i] = 0.f;
  for (int d = 0; d < 32; d++) {
    float4 vv = *(const float4*)(vb + (long long)d * 4096);
    #pragma unroll
    for (int r = 0; r < 8; r++) {
      float wv = wsm[rg * 8 + r][d];
      acc[r][0] += wv * vv.x; acc[r][1] += wv * vv.y;
      acc[r][2] += wv * vv.z; acc[r][3] += wv * vv.w;
    }
  }
  #pragma unroll
  for (int r = 0; r < 8; r++) {
    long long oidx = ((long long)(b * 512 + 256 + h * 32 + rg * 8 + r)) * 4096 + n0;
    float4 ov = {acc[r][0], acc[r][1], acc[r][2], acc[r][3]};
    *(float4*)(out + oidx) = ov;
  }
}

extern "C" void kernel_launch(void* const* d_in, const int* in_sizes, int n_in,
                              void* d_out, int out_size, void* d_ws, size_t ws_size,
                              hipStream_t stream) {
  const float* x    = (const float*)d_in[0];
  const float* modm = (const float*)d_in[1];
  const float* modb = (const float*)d_in[2];
  const float* Wq   = (const float*)d_in[3];
  const float* qkvb = (const float*)d_in[4];
  const float* peqh = (const float*)d_in[5];
  const float* peqw = (const float*)d_in[6];
  const float* pekh = (const float*)d_in[7];
  const float* pekw = (const float*)d_in[8];
  const float* pab  = (const float*)d_in[9];
  const float* pqb  = (const float*)d_in[10];
  float* out = (float*)d_out;

  // ws layout (67 MB total, <= 69.2 MB proven):
  //   [0, 0.75MB)  Wh/Wl u16[768][256] split-bf16 planes
  //   [1MB, 3MB)   logitsP f32[4][128][1024]
  //   [3MB, 67MB)  kv: k packed u32 [16][256][4096], then v fp32 (same region)
  unsigned short* Wh = (unsigned short*)d_ws;
  unsigned short* Wl = Wh + 768 * 256;
  float* logitsP = (float*)((char*)d_ws + (1 << 20));
  float* kv = (float*)((char*)d_ws + 3 * (1 << 20));

  k_wsplit<<<96, 256, 0, stream>>>(Wq, Wh, Wl);
  k_prep<<<4096, 256, 0, stream>>>(x, pab, pqb, out);
  k_qkv<1><<<2048, 256, 32768, stream>>>(Wh, Wl, qkvb, peqh, peqw, pekh, pekw,
                                         modm, modb, out, kv, 0, 4);
  k_logits<<<512, 256, 0, stream>>>((const unsigned*)out, (const unsigned*)kv, logitsP);
  k_qkv<0><<<1024, 256, 16384, stream>>>(Wh, Wl, qkvb, peqh, peqw, pekh, pekw,
                                         modm, modb, out, kv, 512, 2);
  k_pv<<<2048, 256, 0, stream>>>(kv, logitsP, out);
  k_act<<<16384, 256, 0, stream>>>(x, pab, out);
}

// Round 5
// 378.542 us; speedup vs baseline: 1.2864x; 1.2864x over previous
//
#include <hip/hip_runtime.h>

typedef short bf16x8 __attribute__((ext_vector_type(8)));
typedef float f32x4 __attribute__((ext_vector_type(4)));

__device__ __forceinline__ float b2f(unsigned short u) {
  union { unsigned int i; float f; } v; v.i = ((unsigned int)u) << 16; return v.f;
}
__device__ __forceinline__ unsigned short f2b(float f) {
  unsigned int u = __float_as_uint(f);
  u += 0x7fffu + ((u >> 16) & 1u);
  return (unsigned short)(u >> 16);
}
__device__ __forceinline__ float silu_f(float s) { return s / (1.0f + __expf(-s)); }

// split fp32 -> (hi, lo) bf16
__device__ __forceinline__ void split2(float f, unsigned short& h, unsigned short& l) {
  h = f2b(f);
  l = f2b(f - b2f(h));
}

// async 16B/lane global->LDS. LDS dest = wave-uniform base + lane*16 (linear).
__device__ __forceinline__ void gload16(const unsigned short* g, unsigned short* l) {
  __builtin_amdgcn_global_load_lds(
      (const __attribute__((address_space(1))) unsigned int*)g,
      (__attribute__((address_space(3))) unsigned int*)l, 16, 0, 0);
}

// unpack 8 packed (hi | lo<<16) u32 -> hi/lo bf16x8 via v_perm (2 ops per pair)
__device__ __forceinline__ void unpack8(const unsigned* p, bf16x8& hi, bf16x8& lo) {
  uint4 a = *(const uint4*)p;
  uint4 b = *(const uint4*)(p + 4);
  unsigned u[8] = {a.x, a.y, a.z, a.w, b.x, b.y, b.z, b.w};
  unsigned hw[4], lw[4];
  #pragma unroll
  for (int j = 0; j < 4; j++) {
    hw[j] = __builtin_amdgcn_perm(u[2 * j + 1], u[2 * j], 0x05040100u);
    lw[j] = __builtin_amdgcn_perm(u[2 * j + 1], u[2 * j], 0x07060302u);
  }
  hi = *(bf16x8*)hw;
  lo = *(bf16x8*)lw;
}

// K0: split W fp32 -> Wh/Wl bf16 planes [768][256], once.
__global__ __launch_bounds__(256) void k_wsplit(
    const float* __restrict__ W, unsigned short* __restrict__ Wh,
    unsigned short* __restrict__ Wl) {
  int e = (blockIdx.x * 256 + threadIdx.x) * 8;  // 96 blocks * 256 * 8 = 768*256
  float4 a = *(const float4*)(W + e);
  float4 b = *(const float4*)(W + e + 4);
  float v[8] = {a.x, a.y, a.z, a.w, b.x, b.y, b.z, b.w};
  unsigned short h[8], l[8];
  #pragma unroll
  for (int j = 0; j < 8; j++) split2(v[j], h[j], l[j]);
  uint4 ph, pl;
  ph.x = h[0] | ((unsigned)h[1] << 16); ph.y = h[2] | ((unsigned)h[3] << 16);
  ph.z = h[4] | ((unsigned)h[5] << 16); ph.w = h[6] | ((unsigned)h[7] << 16);
  pl.x = l[0] | ((unsigned)l[1] << 16); pl.y = l[2] | ((unsigned)l[3] << 16);
  pl.z = l[4] | ((unsigned)l[5] << 16); pl.w = l[6] | ((unsigned)l[7] << 16);
  *(uint4*)(Wh + e) = ph;
  *(uint4*)(Wl + e) = pl;
}

// K1: T = silu(x + pab) + pqb, written TRANSPOSED as split planes into out[:,256:512]:
//   per batch: Th u16[4096][256] then Tl u16[4096][256] (2MB + 2MB = exactly the region).
__global__ __launch_bounds__(256) void k_prep(
    const float* __restrict__ x, const float* __restrict__ pab,
    const float* __restrict__ pqb, float* __restrict__ out) {
  __shared__ unsigned short th[64 * 64], tl[64 * 64];  // [n][c], sub-chunk swizzled
  int blk = blockIdx.x;
  int nb = blk & 63;
  int cb = (blk >> 6) & 3;
  int b = blk >> 8;
  int n0 = nb * 64, c0 = cb * 64;
  int t = threadIdx.x;
  int nn = (t & 15) * 4;
  #pragma unroll
  for (int p = 0; p < 2; p++) {
    int c = 2 * (p * 16 + (t >> 4));  // even
    float pa0 = pab[c0 + c], pq0 = pqb[c0 + c];
    float pa1 = pab[c0 + c + 1], pq1 = pqb[c0 + c + 1];
    float4 x0 = *(const float4*)(x + ((long long)(b * 256 + c0 + c)) * 4096 + n0 + nn);
    float4 x1 = *(const float4*)(x + ((long long)(b * 256 + c0 + c + 1)) * 4096 + n0 + nn);
    float t0[4] = {silu_f(x0.x + pa0) + pq0, silu_f(x0.y + pa0) + pq0,
                   silu_f(x0.z + pa0) + pq0, silu_f(x0.w + pa0) + pq0};
    float t1[4] = {silu_f(x1.x + pa1) + pq1, silu_f(x1.y + pa1) + pq1,
                   silu_f(x1.z + pa1) + pq1, silu_f(x1.w + pa1) + pq1};
    #pragma unroll
    for (int j = 0; j < 4; j++) {
      int nr = nn + j;
      unsigned short h0, l0, h1, l1;
      split2(t0[j], h0, l0);
      split2(t1[j], h1, l1);
      // physical col: swizzle 8-elem sub-chunk by row (c even => pair stays in chunk)
      int pcol = ((((c >> 3) ^ (nr & 7)) << 3) | (c & 7));
      *(unsigned int*)(th + nr * 64 + pcol) = (unsigned)h0 | ((unsigned)h1 << 16);
      *(unsigned int*)(tl + nr * 64 + pcol) = (unsigned)l0 | ((unsigned)l1 << 16);
    }
  }
  __syncthreads();
  unsigned short* Th = (unsigned short*)(out + ((long long)(b * 512 + 256)) * 4096);
  unsigned short* Tl = Th + 4096 * 256;
  #pragma unroll
  for (int q = 0; q < 2; q++) {
    int s = q * 256 + t;
    int n = s >> 3, sc = s & 7;
    int psc = sc ^ (n & 7);
    uint4 vh = *(const uint4*)(th + n * 64 + psc * 8);
    uint4 vl = *(const uint4*)(tl + n * 64 + psc * 8);
    *(uint4*)(Th + (long long)(n0 + n) * 256 + c0 + sc * 8) = vh;
    *(uint4*)(Tl + (long long)(n0 + n) * 256 + c0 + sc * 8) = vl;
  }
}

// K6 (last): x_preact = silu(x + pab) fp32 -> out[:,0:256]
__global__ __launch_bounds__(256) void k_act(
    const float* __restrict__ x, const float* __restrict__ pab,
    float* __restrict__ out) {
  long long e = ((long long)blockIdx.x * 256 + threadIdx.x) * 4;
  int b = (int)(e >> 20);
  int c = ((int)(e >> 12)) & 255;
  int n = (int)(e & 4095);
  float4 xv = *(const float4*)(x + e);
  float pa = pab[c];
  float4 o = {silu_f(xv.x + pa), silu_f(xv.y + pa), silu_f(xv.z + pa), silu_f(xv.w + pa)};
  *(float4*)(out + ((long long)(b * 512 + c)) * 4096 + n) = o;
}

// K2/K4: GEMM qkv rows [o_base, o_base+obt*128). USE_LO=1 -> 3-term split-bf16.
// 8-wave (512-thread) blocks on a 128x128 tile: halves per-wave register
// pressure (acc[4][2]) and doubles waves/CU at the same 64KB/32KB LDS
// double-buffer -> ~45% occupancy, no spills. Counted vmcnt (T4): prefetch
// stays in flight across barriers; never drain to 0 in the main loop.
//   part 0 (q): +bias+PE, FiLM -> out[:,0:256] packed (hi|lo<<16) u32
//   part 1 (k): +bias+PE      -> kv packed u32
//   part 2 (v): +bias         -> kv fp32
template <int USE_LO>
__global__ __launch_bounds__(512, 4) void k_qkv(
    const unsigned short* __restrict__ Wh, const unsigned short* __restrict__ Wl,
    const float* __restrict__ qkvb,
    const float* __restrict__ peqh, const float* __restrict__ peqw,
    const float* __restrict__ pekh, const float* __restrict__ pekw,
    const float* __restrict__ modm, const float* __restrict__ modb,
    float* __restrict__ out, float* __restrict__ kv,
    int o_base, int obt) {
  extern __shared__ unsigned short sm[];
  const int BUFS = USE_LO ? 16384 : 8192;  // u16 per buffer

  int bx = blockIdx.x;
  int nb = bx & 31;
  int hb = bx >> 5;
  int ob = hb % obt;
  int b = hb / obt;
  int o0 = o_base + ob * 128, n0 = nb * 128;
  int t = threadIdx.x;
  int lane = t & 63, w = t >> 6;   // 8 waves
  int wm = w >> 2, wn = w & 3;     // wave tile: 64 rows x 32 cols
  int l15 = lane & 15, l4 = lane >> 4;

  const unsigned short* Th =
      (const unsigned short*)(out + ((long long)(b * 512 + 256)) * 4096);
  const unsigned short* Tl = Th + 4096 * 256;

  // per-wave staging assignment
  const unsigned short* src;
  int dstoff, row0;
  if (USE_LO) {
    // plane p = w>>1 (0:Ah 1:Al 2:Bh 3:Bl), half hh = w&1 (64 rows each)
    int p = w >> 1, hh = w & 1;
    src = (p == 0) ? Wh : (p == 1) ? Wl : (p == 2) ? Th : Tl;
    row0 = ((p < 2) ? o0 : n0) + hh * 64;
    dstoff = p * 4096 + hh * 2048;
  } else {
    // plane p = w>>2 (0:Ah 1:Bh), quarter qq = w&3 (32 rows each)
    int p = w >> 2, qq = w & 3;
    src = (p == 0) ? Wh : Th;
    row0 = ((p == 0) ? o0 : n0) + qq * 32;
    dstoff = p * 4096 + qq * 1024;
  }
  const int nI = USE_LO ? 4 : 2;  // gload16 instrs per wave per K-step (1KB each)
  // source-side swizzle: lane writes LDS (row=l>>2, chunk=l&3); fetch logical
  // chunk (l&3) ^ ((l>>3)&3) so physical chunk = logical ^ ((row>>1)&3).
  int laneoff = (lane >> 2) * 256 + (((lane & 3) ^ ((lane >> 3) & 3)) << 3);
  const unsigned short* sbase = src + (long long)row0 * 256 + laneoff;

  f32x4 z = {0.f, 0.f, 0.f, 0.f};
  f32x4 acc[4][2];
  #pragma unroll
  for (int i = 0; i < 4; i++)
    #pragma unroll
    for (int j = 0; j < 2; j++) acc[i][j] = z;

  // read-side physical chunk for this lane (row%16 == l15, strip offsets are
  // multiples of 16 so (row>>1)&3 == (l15>>1)&3)
  int sw = (l4 ^ ((l15 >> 1) & 3)) << 3;

  // prologue: stage K-step 0 into buf 0 (stays in flight; counted below)
  #pragma unroll
  for (int i = 0; i < nI; i++) gload16(sbase + i * 4096, sm + dstoff + i * 512);

  int cur = 0;
  for (int step = 0; step < 8; ++step) {
    // issue next K-step's prefetch; wait COUNTED vmcnt: previous batch done,
    // just-issued batch stays in flight across the barrier + MFMA cluster.
    if (step < 7) {
      const unsigned short* sp = sbase + (step + 1) * 32;
      unsigned short* dp = sm + (cur ^ 1) * BUFS + dstoff;
      #pragma unroll
      for (int i = 0; i < nI; i++) gload16(sp + i * 4096, dp + i * 512);
      if (USE_LO) asm volatile("s_waitcnt vmcnt(4)" ::: "memory");
      else        asm volatile("s_waitcnt vmcnt(2)" ::: "memory");
    } else {
      asm volatile("s_waitcnt vmcnt(0)" ::: "memory");
    }
    __builtin_amdgcn_s_barrier();          // everyone's tile-step data in LDS
    __builtin_amdgcn_sched_barrier(0);     // pin ds_reads below the barrier
    unsigned short* Ah = sm + cur * BUFS;
    unsigned short* Al = Ah + 4096;
    unsigned short* Bh = Ah + (USE_LO ? 8192 : 4096);
    unsigned short* Bl = Ah + 12288;
    bf16x8 ah[4], al[4], bh[2], bl[2];
    #pragma unroll
    for (int i = 0; i < 4; i++) {
      int rowA = (wm * 64 + i * 16 + l15) * 32;
      ah[i] = *(const bf16x8*)(Ah + rowA + sw);
      if (USE_LO) al[i] = *(const bf16x8*)(Al + rowA + sw);
    }
    #pragma unroll
    for (int j = 0; j < 2; j++) {
      int rowB = (wn * 32 + j * 16 + l15) * 32;
      bh[j] = *(const bf16x8*)(Bh + rowB + sw);
      if (USE_LO) bl[j] = *(const bf16x8*)(Bl + rowB + sw);
    }
    #pragma unroll
    for (int i = 0; i < 4; i++)
      #pragma unroll
      for (int j = 0; j < 2; j++) {
        acc[i][j] = __builtin_amdgcn_mfma_f32_16x16x32_bf16(ah[i], bh[j], acc[i][j], 0, 0, 0);
        if (USE_LO) {
          acc[i][j] = __builtin_amdgcn_mfma_f32_16x16x32_bf16(ah[i], bl[j], acc[i][j], 0, 0, 0);
          acc[i][j] = __builtin_amdgcn_mfma_f32_16x16x32_bf16(al[i], bh[j], acc[i][j], 0, 0, 0);
        }
      }
    __builtin_amdgcn_sched_barrier(0);
    // reads of buf `cur` consumed by MFMA; bare barrier, NO vmcnt drain.
    __builtin_amdgcn_s_barrier();
    cur ^= 1;
  }

  int part = o0 >> 8;
  #pragma unroll
  for (int i = 0; i < 4; i++) {
    #pragma unroll
    for (int r = 0; r < 4; r++) {
      int o = o0 + wm * 64 + i * 16 + l4 * 4 + r;
      int cch = o & 255;
      float bias = qkvb[o];
      float mm = 0.f, mb = 0.f;
      if (part == 0) { mm = modm[b * 256 + cch]; mb = modb[b * 256 + cch]; }
      #pragma unroll
      for (int j = 0; j < 2; j++) {
        int n = n0 + wn * 32 + j * 16 + l15;
        float v = acc[i][j][r] + bias;
        int hh = n >> 6, ww = n & 63;
        if (part == 0) {
          v += peqh[cch * 64 + hh] + peqw[cch * 64 + ww];
          v = v * mm + mb;
          unsigned short h, l; split2(v, h, l);
          ((unsigned*)out)[((long long)(b * 512 + cch)) * 4096 + n] =
              (unsigned)h | ((unsigned)l << 16);
        } else if (part == 1) {
          v += pekh[cch * 64 + hh] + pekw[cch * 64 + ww];
          unsigned short h, l; split2(v, h, l);
          ((unsigned*)kv)[((long long)(b * 256 + cch)) * 4096 + n] =
              (unsigned)h | ((unsigned)l << 16);
        } else {
          kv[((long long)(b * 256 + cch)) * 4096 + n] = v;
        }
      }
    }
  }
}

// K3: logitsP[chunk][b,h,c,d] = scale * sum_{n in chunk} q[c,n] k[d,n]
// q, k read as packed split-bf16 (written by k_qkv) -> v_perm unpack, no cvt.
__global__ __launch_bounds__(256) void k_logits(
    const unsigned* __restrict__ qp, const unsigned* __restrict__ kp,
    float* __restrict__ logitsP) {
  int bx = blockIdx.x;
  int chunk = bx & 3, bh = bx >> 2;
  int b = bh >> 3, h = bh & 7;
  int t = threadIdx.x, lane = t & 63, w = t >> 6;
  int l15 = lane & 15, l4 = lane >> 4;
  const unsigned* qb = qp + ((long long)(b * 512 + h * 32)) * 4096;
  const unsigned* kb = kp + ((long long)(b * 256 + h * 32)) * 4096;
  f32x4 z = {0.f, 0.f, 0.f, 0.f};
  f32x4 acc[2][2] = {z, z, z, z};
  int nstep0 = chunk * 1024 + w * 256;
  for (int it = 0; it < 8; it++) {
    int n = nstep0 + it * 32 + l4 * 8;
    bf16x8 qh0, ql0, qh1, ql1, kh0, kl0, kh1, kl1;
    unpack8(qb + (long long)l15 * 4096 + n, qh0, ql0);
    unpack8(qb + (long long)(16 + l15) * 4096 + n, qh1, ql1);
    unpack8(kb + (long long)l15 * 4096 + n, kh0, kl0);
    unpack8(kb + (long long)(16 + l15) * 4096 + n, kh1, kl1);
    acc[0][0] = __builtin_amdgcn_mfma_f32_16x16x32_bf16(qh0, kh0, acc[0][0], 0, 0, 0);
    acc[0][0] = __builtin_amdgcn_mfma_f32_16x16x32_bf16(qh0, kl0, acc[0][0], 0, 0, 0);
    acc[0][0] = __builtin_amdgcn_mfma_f32_16x16x32_bf16(ql0, kh0, acc[0][0], 0, 0, 0);
    acc[0][1] = __builtin_amdgcn_mfma_f32_16x16x32_bf16(qh0, kh1, acc[0][1], 0, 0, 0);
    acc[0][1] = __builtin_amdgcn_mfma_f32_16x16x32_bf16(qh0, kl1, acc[0][1], 0, 0, 0);
    acc[0][1] = __builtin_amdgcn_mfma_f32_16x16x32_bf16(ql0, kh1, acc[0][1], 0, 0, 0);
    acc[1][0] = __builtin_amdgcn_mfma_f32_16x16x32_bf16(qh1, kh0, acc[1][0], 0, 0, 0);
    acc[1][0] = __builtin_amdgcn_mfma_f32_16x16x32_bf16(qh1, kl0, acc[1][0], 0, 0, 0);
    acc[1][0] = __builtin_amdgcn_mfma_f32_16x16x32_bf16(ql1, kh0, acc[1][0], 0, 0, 0);
    acc[1][1] = __builtin_amdgcn_mfma_f32_16x16x32_bf16(qh1, kh1, acc[1][1], 0, 0, 0);
    acc[1][1] = __builtin_amdgcn_mfma_f32_16x16x32_bf16(qh1, kl1, acc[1][1], 0, 0, 0);
    acc[1][1] = __builtin_amdgcn_mfma_f32_16x16x32_bf16(ql1, kh1, acc[1][1], 0, 0, 0);
  }
  __shared__ float red[4][1024];
  #pragma unroll
  for (int ch = 0; ch < 2; ch++)
    #pragma unroll
    for (int dh = 0; dh < 2; dh++)
      #pragma unroll
      for (int r = 0; r < 4; r++) {
        int crow = ch * 16 + l4 * 4 + r;
        int dcol = dh * 16 + l15;
        red[w][crow * 32 + dcol] = acc[ch][dh][r];
      }
  __syncthreads();
  const float scale = 0.1767766952966369f;  // 1/sqrt(32)
  #pragma unroll
  for (int i = 0; i < 4; i++) {
    int idx = i * 256 + t;
    float s = (red[0][idx] + red[1][idx] + red[2][idx] + red[3][idx]) * scale;
    logitsP[(long long)chunk * 131072 + bh * 1024 + idx] = s;
  }
}

// K5: softmax (sum 4 partials) + out = weights @ v -> out[:,256:512] fp32
__global__ __launch_bounds__(256) void k_pv(
    const float* __restrict__ kv,    // v
    const float* __restrict__ logitsP,
    float* __restrict__ out) {
  int bx = blockIdx.x;
  int ntile = bx & 15, bh = bx >> 4;
  int b = bh >> 3, h = bh & 7;
  int t = threadIdx.x;
  __shared__ float raw[32][33];   // [c][d], padded: serial reads conflict-free
  __shared__ float wsm[32][33];
  #pragma unroll
  for (int i = 0; i < 4; i++) {
    int idx = i * 256 + t;
    float s = logitsP[bh * 1024 + idx] + logitsP[131072 + bh * 1024 + idx]
            + logitsP[262144 + bh * 1024 + idx] + logitsP[393216 + bh * 1024 + idx];
    raw[idx >> 5][idx & 31] = s;
  }
  __syncthreads();
  if (t < 32) {
    float mx = -1e30f;
    for (int d = 0; d < 32; d++) mx = fmaxf(mx, raw[t][d]);
    float e[32]; float s = 0.f;
    for (int d = 0; d < 32; d++) { e[d] = __expf(raw[t][d] - mx); s += e[d]; }
    float inv = 1.0f / s;
    for (int d = 0; d < 32; d++) wsm[t][d] = e[d] * inv;
  }
  __syncthreads();
  int rg = t >> 6;          // wave-uniform -> wsm broadcast
  int nl = (t & 63) * 4;
  int n0 = ntile * 256 + nl;
  const float* vb = kv + ((long long)(b * 256 + h * 32)) * 4096 + n0;
  float acc[8][4];
  #pragma unroll
  for (int r = 0; r < 8; r++)
    #pragma unroll
    for (int i = 0; i < 4; i++) acc[r][i] = 0.f;
  for (int d = 0; d < 32; d++) {
    float4 vv = *(const float4*)(vb + (long long)d * 4096);
    #pragma unroll
    for (int r = 0; r < 8; r++) {
      float wv = wsm[rg * 8 + r][d];
      acc[r][0] += wv * vv.x; acc[r][1] += wv * vv.y;
      acc[r][2] += wv * vv.z; acc[r][3] += wv * vv.w;
    }
  }
  #pragma unroll
  for (int r = 0; r < 8; r++) {
    long long oidx = ((long long)(b * 512 + 256 + h * 32 + rg * 8 + r)) * 4096 + n0;
    float4 ov = {acc[r][0], acc[r][1], acc[r][2], acc[r][3]};
    *(float4*)(out + oidx) = ov;
  }
}

extern "C" void kernel_launch(void* const* d_in, const int* in_sizes, int n_in,
                              void* d_out, int out_size, void* d_ws, size_t ws_size,
                              hipStream_t stream) {
  const float* x    = (const float*)d_in[0];
  const float* modm = (const float*)d_in[1];
  const float* modb = (const float*)d_in[2];
  const float* Wq   = (const float*)d_in[3];
  const float* qkvb = (const float*)d_in[4];
  const float* peqh = (const float*)d_in[5];
  const float* peqw = (const float*)d_in[6];
  const float* pekh = (const float*)d_in[7];
  const float* pekw = (const float*)d_in[8];
  const float* pab  = (const float*)d_in[9];
  const float* pqb  = (const float*)d_in[10];
  float* out = (float*)d_out;

  // ws layout (67 MB total, <= 69.2 MB proven):
  //   [0, 0.75MB)  Wh/Wl u16[768][256] split-bf16 planes
  //   [1MB, 3MB)   logitsP f32[4][128][1024]
  //   [3MB, 67MB)  kv: k packed u32 [16][256][4096], then v fp32 (same region)
  unsigned short* Wh = (unsigned short*)d_ws;
  unsigned short* Wl = Wh + 768 * 256;
  float* logitsP = (float*)((char*)d_ws + (1 << 20));
  float* kv = (float*)((char*)d_ws + 3 * (1 << 20));

  k_wsplit<<<96, 256, 0, stream>>>(Wq, Wh, Wl);
  k_prep<<<4096, 256, 0, stream>>>(x, pab, pqb, out);
  k_qkv<1><<<2048, 512, 65536, stream>>>(Wh, Wl, qkvb, peqh, peqw, pekh, pekw,
                                         modm, modb, out, kv, 0, 4);
  k_logits<<<512, 256, 0, stream>>>((const unsigned*)out, (const unsigned*)kv, logitsP);
  k_qkv<0><<<1024, 512, 32768, stream>>>(Wh, Wl, qkvb, peqh, peqw, pekh, pekw,
                                         modm, modb, out, kv, 512, 2);
  k_pv<<<2048, 256, 0, stream>>>(kv, logitsP, out);
  k_act<<<16384, 256, 0, stream>>>(x, pab, out);
}

// Round 6
// 347.641 us; speedup vs baseline: 1.4007x; 1.0889x over previous
//
#include <hip/hip_runtime.h>

typedef short bf16x8 __attribute__((ext_vector_type(8)));
typedef float f32x4 __attribute__((ext_vector_type(4)));

__device__ __forceinline__ float b2f(unsigned short u) {
  union { unsigned int i; float f; } v; v.i = ((unsigned int)u) << 16; return v.f;
}
__device__ __forceinline__ unsigned short f2b(float f) {
  unsigned int u = __float_as_uint(f);
  u += 0x7fffu + ((u >> 16) & 1u);
  return (unsigned short)(u >> 16);
}
__device__ __forceinline__ float silu_f(float s) { return s / (1.0f + __expf(-s)); }

// split fp32 -> (hi, lo) bf16
__device__ __forceinline__ void split2(float f, unsigned short& h, unsigned short& l) {
  h = f2b(f);
  l = f2b(f - b2f(h));
}

// async 16B/lane global->LDS. LDS dest = wave-uniform base + lane*16 (linear).
__device__ __forceinline__ void gload16(const unsigned short* g, unsigned short* l) {
  __builtin_amdgcn_global_load_lds(
      (const __attribute__((address_space(1))) unsigned int*)g,
      (__attribute__((address_space(3))) unsigned int*)l, 16, 0, 0);
}

// unpack 8 packed (hi | lo<<16) u32 -> hi/lo bf16x8 via v_perm (2 ops per pair)
__device__ __forceinline__ void unpack8(const unsigned* p, bf16x8& hi, bf16x8& lo) {
  uint4 a = *(const uint4*)p;
  uint4 b = *(const uint4*)(p + 4);
  unsigned u[8] = {a.x, a.y, a.z, a.w, b.x, b.y, b.z, b.w};
  unsigned hw[4], lw[4];
  #pragma unroll
  for (int j = 0; j < 4; j++) {
    hw[j] = __builtin_amdgcn_perm(u[2 * j + 1], u[2 * j], 0x05040100u);
    lw[j] = __builtin_amdgcn_perm(u[2 * j + 1], u[2 * j], 0x07060302u);
  }
  hi = *(bf16x8*)hw;
  lo = *(bf16x8*)lw;
}

// K0: split W fp32 -> Wh/Wl bf16 planes [768][256], once.
__global__ __launch_bounds__(256) void k_wsplit(
    const float* __restrict__ W, unsigned short* __restrict__ Wh,
    unsigned short* __restrict__ Wl) {
  int e = (blockIdx.x * 256 + threadIdx.x) * 8;  // 96 blocks * 256 * 8 = 768*256
  float4 a = *(const float4*)(W + e);
  float4 b = *(const float4*)(W + e + 4);
  float v[8] = {a.x, a.y, a.z, a.w, b.x, b.y, b.z, b.w};
  unsigned short h[8], l[8];
  #pragma unroll
  for (int j = 0; j < 8; j++) split2(v[j], h[j], l[j]);
  uint4 ph, pl;
  ph.x = h[0] | ((unsigned)h[1] << 16); ph.y = h[2] | ((unsigned)h[3] << 16);
  ph.z = h[4] | ((unsigned)h[5] << 16); ph.w = h[6] | ((unsigned)h[7] << 16);
  pl.x = l[0] | ((unsigned)l[1] << 16); pl.y = l[2] | ((unsigned)l[3] << 16);
  pl.z = l[4] | ((unsigned)l[5] << 16); pl.w = l[6] | ((unsigned)l[7] << 16);
  *(uint4*)(Wh + e) = ph;
  *(uint4*)(Wl + e) = pl;
}

// K1: fused prep+act:
//   x_preact = silu(x + pab) fp32 -> out[:,0:256]   (q no longer uses this region)
//   T = x_preact + pqb, TRANSPOSED split planes -> out[:,256:512]
//     per batch: Th u16[4096][256] then Tl u16[4096][256]
__global__ __launch_bounds__(256) void k_prep(
    const float* __restrict__ x, const float* __restrict__ pab,
    const float* __restrict__ pqb, float* __restrict__ out) {
  __shared__ unsigned short th[64 * 64], tl[64 * 64];  // [n][c], sub-chunk swizzled
  int blk = blockIdx.x;
  int nb = blk & 63;
  int cb = (blk >> 6) & 3;
  int b = blk >> 8;
  int n0 = nb * 64, c0 = cb * 64;
  int t = threadIdx.x;
  int nn = (t & 15) * 4;
  #pragma unroll
  for (int p = 0; p < 2; p++) {
    int c = 2 * (p * 16 + (t >> 4));  // even
    float pa0 = pab[c0 + c], pq0 = pqb[c0 + c];
    float pa1 = pab[c0 + c + 1], pq1 = pqb[c0 + c + 1];
    float4 x0 = *(const float4*)(x + ((long long)(b * 256 + c0 + c)) * 4096 + n0 + nn);
    float4 x1 = *(const float4*)(x + ((long long)(b * 256 + c0 + c + 1)) * 4096 + n0 + nn);
    float s0[4] = {silu_f(x0.x + pa0), silu_f(x0.y + pa0),
                   silu_f(x0.z + pa0), silu_f(x0.w + pa0)};
    float s1[4] = {silu_f(x1.x + pa1), silu_f(x1.y + pa1),
                   silu_f(x1.z + pa1), silu_f(x1.w + pa1)};
    float4 sv0 = {s0[0], s0[1], s0[2], s0[3]};
    float4 sv1 = {s1[0], s1[1], s1[2], s1[3]};
    *(float4*)(out + ((long long)(b * 512 + c0 + c)) * 4096 + n0 + nn) = sv0;
    *(float4*)(out + ((long long)(b * 512 + c0 + c + 1)) * 4096 + n0 + nn) = sv1;
    float t0[4] = {s0[0] + pq0, s0[1] + pq0, s0[2] + pq0, s0[3] + pq0};
    float t1[4] = {s1[0] + pq1, s1[1] + pq1, s1[2] + pq1, s1[3] + pq1};
    #pragma unroll
    for (int j = 0; j < 4; j++) {
      int nr = nn + j;
      unsigned short h0, l0, h1, l1;
      split2(t0[j], h0, l0);
      split2(t1[j], h1, l1);
      int pcol = ((((c >> 3) ^ (nr & 7)) << 3) | (c & 7));
      *(unsigned int*)(th + nr * 64 + pcol) = (unsigned)h0 | ((unsigned)h1 << 16);
      *(unsigned int*)(tl + nr * 64 + pcol) = (unsigned)l0 | ((unsigned)l1 << 16);
    }
  }
  __syncthreads();
  unsigned short* Th = (unsigned short*)(out + ((long long)(b * 512 + 256)) * 4096);
  unsigned short* Tl = Th + 4096 * 256;
  #pragma unroll
  for (int q = 0; q < 2; q++) {
    int s = q * 256 + t;
    int n = s >> 3, sc = s & 7;
    int psc = sc ^ (n & 7);
    uint4 vh = *(const uint4*)(th + n * 64 + psc * 8);
    uint4 vl = *(const uint4*)(tl + n * 64 + psc * 8);
    *(uint4*)(Th + (long long)(n0 + n) * 256 + c0 + sc * 8) = vh;
    *(uint4*)(Tl + (long long)(n0 + n) * 256 + c0 + sc * 8) = vl;
  }
}

// K2: fused q/k GEMM + logits. One block = (b, head, ntile of 128 n).
// Main loop: 64 A-rows (32 q + 32 k of this head) x 128 n, 3-term split-bf16,
// exact round-5 MFMA structure (bit-identical q,k). Epilogue: bias+PE (+FiLM
// for q) in registers, packed (hi|lo) -> swizzled LDS tile. Logits phase:
// q·k^T over this n-tile (3-term, same as old k_logits), LDS-reduce across
// the 4 waves, atomicAdd scaled partial into logits[b,h,32,32].
__global__ __launch_bounds__(256) void k_qkl(
    const unsigned short* __restrict__ Wh, const unsigned short* __restrict__ Wl,
    const float* __restrict__ qkvb,
    const float* __restrict__ peqh, const float* __restrict__ peqw,
    const float* __restrict__ pekh, const float* __restrict__ pekw,
    const float* __restrict__ modm, const float* __restrict__ modb,
    const float* __restrict__ outT, float* __restrict__ logits) {
  __shared__ __align__(16) unsigned short stg[12288];  // 24KB: Ah|Al|Bh|Bl
  __shared__ __align__(16) unsigned qk[64 * 128];      // 32KB packed q/k tile
  int bx = blockIdx.x;
  int ntile = bx & 31, h = (bx >> 5) & 7, b = bx >> 8;
  int n0 = ntile * 128;
  int t = threadIdx.x, lane = t & 63, w = t >> 6;
  int l15 = lane & 15, l4 = lane >> 4;

  const unsigned short* Th =
      (const unsigned short*)(outT + ((long long)(b * 512 + 256)) * 4096);
  const unsigned short* Tl = Th + 4096 * 256;

  // 24 staging chunks (16 rows x 32 u16 = 1KB): 0-3 Ah, 4-7 Al, 8-15 Bh, 16-23 Bl.
  // A rows: 0-31 = q (W rows h*32..), 32-63 = k (W rows 256+h*32..).
  const unsigned short* csrc[6];
  unsigned short* cdst[6];
  int lrow = lane >> 2;
  int lslot = ((lane & 3) ^ ((lane >> 3) & 3)) * 8;  // source-side swizzle
  #pragma unroll
  for (int i = 0; i < 6; i++) {
    int c = w * 6 + i;
    const unsigned short* plane;
    int rowb, ldsoff;
    if (c < 8) {
      plane = (c & 4) ? Wl : Wh;
      int sub = c & 3;
      rowb = h * 32 + ((sub & 2) ? 256 : 0) + (sub & 1) * 16;
      ldsoff = c * 512;
    } else {
      int ci = c - 8;
      plane = (ci & 8) ? Tl : Th;
      rowb = n0 + (ci & 7) * 16;
      ldsoff = 4096 + ci * 512;
    }
    csrc[i] = plane + (long long)(rowb + lrow) * 256 + lslot;
    cdst[i] = stg + ldsoff;
  }

  int sw = (l4 ^ ((l15 >> 1) & 3)) << 3;  // read-side swizzle
  f32x4 z = {0.f, 0.f, 0.f, 0.f};
  f32x4 acc[4][2];
  #pragma unroll
  for (int i = 0; i < 4; i++)
    #pragma unroll
    for (int j = 0; j < 2; j++) acc[i][j] = z;

  for (int step = 0; step < 8; ++step) {
    int k0 = step * 32;
    #pragma unroll
    for (int i = 0; i < 6; i++) gload16(csrc[i] + k0, cdst[i]);
    __syncthreads();
    bf16x8 ah[4], al[4], bh[2], bl[2];
    #pragma unroll
    for (int i = 0; i < 4; i++) {
      int ro = (i * 16 + l15) * 32 + sw;
      ah[i] = *(const bf16x8*)(stg + ro);
      al[i] = *(const bf16x8*)(stg + 2048 + ro);
    }
    #pragma unroll
    for (int j = 0; j < 2; j++) {
      int ro = (w * 32 + j * 16 + l15) * 32 + sw;
      bh[j] = *(const bf16x8*)(stg + 4096 + ro);
      bl[j] = *(const bf16x8*)(stg + 8192 + ro);
    }
    #pragma unroll
    for (int i = 0; i < 4; i++)
      #pragma unroll
      for (int j = 0; j < 2; j++) {
        acc[i][j] = __builtin_amdgcn_mfma_f32_16x16x32_bf16(ah[i], bh[j], acc[i][j], 0, 0, 0);
        acc[i][j] = __builtin_amdgcn_mfma_f32_16x16x32_bf16(ah[i], bl[j], acc[i][j], 0, 0, 0);
        acc[i][j] = __builtin_amdgcn_mfma_f32_16x16x32_bf16(al[i], bh[j], acc[i][j], 0, 0, 0);
      }
    __syncthreads();
  }

  // epilogue: bias + PE (+FiLM for q rows), pack, store to swizzled qk tile
  int b256 = b * 256;
  #pragma unroll
  for (int i = 0; i < 4; i++) {
    #pragma unroll
    for (int r = 0; r < 4; r++) {
      int row = i * 16 + l4 * 4 + r;  // 0..63; i<2 -> q, i>=2 -> k (wave-uniform)
      int cch = h * 32 + (row & 31);
      float bias = qkvb[(row & 32) ? (256 + cch) : cch];
      float mm = 0.f, mb = 0.f;
      if (row < 32) { mm = modm[b256 + cch]; mb = modb[b256 + cch]; }
      #pragma unroll
      for (int j = 0; j < 2; j++) {
        int nl = w * 32 + j * 16 + l15;
        int n = n0 + nl;
        int hh = n >> 6, ww = n & 63;
        float v = acc[i][j][r] + bias;
        if (row < 32) {
          v += peqh[cch * 64 + hh] + peqw[cch * 64 + ww];
          v = v * mm + mb;
        } else {
          v += pekh[cch * 64 + hh] + pekw[cch * 64 + ww];
        }
        unsigned short hi_, lo_;
        split2(v, hi_, lo_);
        int pch = (nl >> 3) ^ (row & 15);  // chunk swizzle (8 u32 = 32B chunks)
        qk[row * 128 + pch * 8 + (nl & 7)] = (unsigned)hi_ | ((unsigned)lo_ << 16);
      }
    }
  }
  __syncthreads();

  // logits partial: q(32 x 128n) . k(32 x 128n)^T; wave w covers n-slice w*32..
  f32x4 acc2[2][2] = {z, z, z, z};
  int chn = w * 4 + l4;
  bf16x8 qh[2], ql[2], kh[2], kl[2];
  #pragma unroll
  for (int i2 = 0; i2 < 2; i2++) {
    int row = i2 * 16 + l15;
    unpack8(qk + row * 128 + ((chn ^ l15) << 3), qh[i2], ql[i2]);
    unpack8(qk + (row + 32) * 128 + ((chn ^ l15) << 3), kh[i2], kl[i2]);
  }
  acc2[0][0] = __builtin_amdgcn_mfma_f32_16x16x32_bf16(qh[0], kh[0], acc2[0][0], 0, 0, 0);
  acc2[0][0] = __builtin_amdgcn_mfma_f32_16x16x32_bf16(qh[0], kl[0], acc2[0][0], 0, 0, 0);
  acc2[0][0] = __builtin_amdgcn_mfma_f32_16x16x32_bf16(ql[0], kh[0], acc2[0][0], 0, 0, 0);
  acc2[0][1] = __builtin_amdgcn_mfma_f32_16x16x32_bf16(qh[0], kh[1], acc2[0][1], 0, 0, 0);
  acc2[0][1] = __builtin_amdgcn_mfma_f32_16x16x32_bf16(qh[0], kl[1], acc2[0][1], 0, 0, 0);
  acc2[0][1] = __builtin_amdgcn_mfma_f32_16x16x32_bf16(ql[0], kh[1], acc2[0][1], 0, 0, 0);
  acc2[1][0] = __builtin_amdgcn_mfma_f32_16x16x32_bf16(qh[1], kh[0], acc2[1][0], 0, 0, 0);
  acc2[1][0] = __builtin_amdgcn_mfma_f32_16x16x32_bf16(qh[1], kl[0], acc2[1][0], 0, 0, 0);
  acc2[1][0] = __builtin_amdgcn_mfma_f32_16x16x32_bf16(ql[1], kh[0], acc2[1][0], 0, 0, 0);
  acc2[1][1] = __builtin_amdgcn_mfma_f32_16x16x32_bf16(qh[1], kh[1], acc2[1][1], 0, 0, 0);
  acc2[1][1] = __builtin_amdgcn_mfma_f32_16x16x32_bf16(qh[1], kl[1], acc2[1][1], 0, 0, 0);
  acc2[1][1] = __builtin_amdgcn_mfma_f32_16x16x32_bf16(ql[1], kh[1], acc2[1][1], 0, 0, 0);

  // cross-wave reduce (reuse staging LDS, free now) + atomic accumulate
  float* red = (float*)stg;  // 4 x 1024 floats = 16KB
  #pragma unroll
  for (int i2 = 0; i2 < 2; i2++)
    #pragma unroll
    for (int j2 = 0; j2 < 2; j2++)
      #pragma unroll
      for (int r = 0; r < 4; r++)
        red[w * 1024 + (i2 * 16 + l4 * 4 + r) * 32 + j2 * 16 + l15] = acc2[i2][j2][r];
  __syncthreads();
  const float scale = 0.1767766952966369f;  // 1/sqrt(32)
  int bhid = b * 8 + h;
  #pragma unroll
  for (int i = 0; i < 4; i++) {
    int idx = i * 256 + t;
    float s = (red[idx] + red[1024 + idx] + red[2048 + idx] + red[3072 + idx]) * scale;
    atomicAdd(logits + (long long)bhid * 1024 + idx, s);
  }
}

// K3 (v GEMM): round-5 k_qkv kept verbatim, only USE_LO=0 instantiated.
template <int USE_LO>
__global__ __launch_bounds__(512, 4) void k_qkv(
    const unsigned short* __restrict__ Wh, const unsigned short* __restrict__ Wl,
    const float* __restrict__ qkvb,
    const float* __restrict__ peqh, const float* __restrict__ peqw,
    const float* __restrict__ pekh, const float* __restrict__ pekw,
    const float* __restrict__ modm, const float* __restrict__ modb,
    float* __restrict__ out, float* __restrict__ kv,
    int o_base, int obt) {
  extern __shared__ unsigned short sm[];
  const int BUFS = USE_LO ? 16384 : 8192;

  int bx = blockIdx.x;
  int nb = bx & 31;
  int hb = bx >> 5;
  int ob = hb % obt;
  int b = hb / obt;
  int o0 = o_base + ob * 128, n0 = nb * 128;
  int t = threadIdx.x;
  int lane = t & 63, w = t >> 6;
  int wm = w >> 2, wn = w & 3;
  int l15 = lane & 15, l4 = lane >> 4;

  const unsigned short* Th =
      (const unsigned short*)(out + ((long long)(b * 512 + 256)) * 4096);
  const unsigned short* Tl = Th + 4096 * 256;

  const unsigned short* src;
  int dstoff, row0;
  if (USE_LO) {
    int p = w >> 1, hh = w & 1;
    src = (p == 0) ? Wh : (p == 1) ? Wl : (p == 2) ? Th : Tl;
    row0 = ((p < 2) ? o0 : n0) + hh * 64;
    dstoff = p * 4096 + hh * 2048;
  } else {
    int p = w >> 2, qq = w & 3;
    src = (p == 0) ? Wh : Th;
    row0 = ((p == 0) ? o0 : n0) + qq * 32;
    dstoff = p * 4096 + qq * 1024;
  }
  const int nI = USE_LO ? 4 : 2;
  int laneoff = (lane >> 2) * 256 + (((lane & 3) ^ ((lane >> 3) & 3)) << 3);
  const unsigned short* sbase = src + (long long)row0 * 256 + laneoff;

  f32x4 z = {0.f, 0.f, 0.f, 0.f};
  f32x4 acc[4][2];
  #pragma unroll
  for (int i = 0; i < 4; i++)
    #pragma unroll
    for (int j = 0; j < 2; j++) acc[i][j] = z;

  int sw = (l4 ^ ((l15 >> 1) & 3)) << 3;

  #pragma unroll
  for (int i = 0; i < nI; i++) gload16(sbase + i * 4096, sm + dstoff + i * 512);

  int cur = 0;
  for (int step = 0; step < 8; ++step) {
    if (step < 7) {
      const unsigned short* sp = sbase + (step + 1) * 32;
      unsigned short* dp = sm + (cur ^ 1) * BUFS + dstoff;
      #pragma unroll
      for (int i = 0; i < nI; i++) gload16(sp + i * 4096, dp + i * 512);
      if (USE_LO) asm volatile("s_waitcnt vmcnt(4)" ::: "memory");
      else        asm volatile("s_waitcnt vmcnt(2)" ::: "memory");
    } else {
      asm volatile("s_waitcnt vmcnt(0)" ::: "memory");
    }
    __builtin_amdgcn_s_barrier();
    __builtin_amdgcn_sched_barrier(0);
    unsigned short* Ah = sm + cur * BUFS;
    unsigned short* Al = Ah + 4096;
    unsigned short* Bh = Ah + (USE_LO ? 8192 : 4096);
    unsigned short* Bl = Ah + 12288;
    bf16x8 ah[4], al[4], bh[2], bl[2];
    #pragma unroll
    for (int i = 0; i < 4; i++) {
      int rowA = (wm * 64 + i * 16 + l15) * 32;
      ah[i] = *(const bf16x8*)(Ah + rowA + sw);
      if (USE_LO) al[i] = *(const bf16x8*)(Al + rowA + sw);
    }
    #pragma unroll
    for (int j = 0; j < 2; j++) {
      int rowB = (wn * 32 + j * 16 + l15) * 32;
      bh[j] = *(const bf16x8*)(Bh + rowB + sw);
      if (USE_LO) bl[j] = *(const bf16x8*)(Bl + rowB + sw);
    }
    #pragma unroll
    for (int i = 0; i < 4; i++)
      #pragma unroll
      for (int j = 0; j < 2; j++) {
        acc[i][j] = __builtin_amdgcn_mfma_f32_16x16x32_bf16(ah[i], bh[j], acc[i][j], 0, 0, 0);
        if (USE_LO) {
          acc[i][j] = __builtin_amdgcn_mfma_f32_16x16x32_bf16(ah[i], bl[j], acc[i][j], 0, 0, 0);
          acc[i][j] = __builtin_amdgcn_mfma_f32_16x16x32_bf16(al[i], bh[j], acc[i][j], 0, 0, 0);
        }
      }
    __builtin_amdgcn_sched_barrier(0);
    __builtin_amdgcn_s_barrier();
    cur ^= 1;
  }

  int part = o0 >> 8;
  #pragma unroll
  for (int i = 0; i < 4; i++) {
    #pragma unroll
    for (int r = 0; r < 4; r++) {
      int o = o0 + wm * 64 + i * 16 + l4 * 4 + r;
      int cch = o & 255;
      float bias = qkvb[o];
      float mm = 0.f, mb = 0.f;
      if (part == 0) { mm = modm[b * 256 + cch]; mb = modb[b * 256 + cch]; }
      #pragma unroll
      for (int j = 0; j < 2; j++) {
        int n = n0 + wn * 32 + j * 16 + l15;
        float v = acc[i][j][r] + bias;
        int hh = n >> 6, ww = n & 63;
        if (part == 0) {
          v += peqh[cch * 64 + hh] + peqw[cch * 64 + ww];
          v = v * mm + mb;
          unsigned short h, l; split2(v, h, l);
          ((unsigned*)out)[((long long)(b * 512 + cch)) * 4096 + n] =
              (unsigned)h | ((unsigned)l << 16);
        } else if (part == 1) {
          v += pekh[cch * 64 + hh] + pekw[cch * 64 + ww];
          unsigned short h, l; split2(v, h, l);
          ((unsigned*)kv)[((long long)(b * 256 + cch)) * 4096 + n] =
              (unsigned)h | ((unsigned)l << 16);
        } else {
          kv[((long long)(b * 256 + cch)) * 4096 + n] = v;
        }
      }
    }
  }
}

// K4: softmax (logits already summed by atomics, already scaled) + weights @ v
__global__ __launch_bounds__(256) void k_pv(
    const float* __restrict__ kv,    // v
    const float* __restrict__ logits,
    float* __restrict__ out) {
  int bx = blockIdx.x;
  int ntile = bx & 15, bh = bx >> 4;
  int b = bh >> 3, h = bh & 7;
  int t = threadIdx.x;
  __shared__ float raw[32][33];   // [c][d], padded: serial reads conflict-free
  __shared__ float wsm[32][33];
  #pragma unroll
  for (int i = 0; i < 4; i++) {
    int idx = i * 256 + t;
    raw[idx >> 5][idx & 31] = logits[(long long)bh * 1024 + idx];
  }
  __syncthreads();
  if (t < 32) {
    float mx = -1e30f;
    for (int d = 0; d < 32; d++) mx = fmaxf(mx, raw[t][d]);
    float e[32]; float s = 0.f;
    for (int d = 0; d < 32; d++) { e[d] = __expf(raw[t][d] - mx); s += e[d]; }
    float inv = 1.0f / s;
    for (int d = 0; d < 32; d++) wsm[t][d] = e[d] * inv;
  }
  __syncthreads();
  int rg = t >> 6;          // wave-uniform -> wsm broadcast
  int nl = (t & 63) * 4;
  int n0 = ntile * 256 + nl;
  const float* vb = kv + ((long long)(b * 256 + h * 32)) * 4096 + n0;
  float acc[8][4];
  #pragma unroll
  for (int r = 0; r < 8; r++)
    #pragma unroll
    for (int i = 0; i < 4; i++) acc[r][i] = 0.f;
  for (int d = 0; d < 32; d++) {
    float4 vv = *(const float4*)(vb + (long long)d * 4096);
    #pragma unroll
    for (int r = 0; r < 8; r++) {
      float wv = wsm[rg * 8 + r][d];
      acc[r][0] += wv * vv.x; acc[r][1] += wv * vv.y;
      acc[r][2] += wv * vv.z; acc[r][3] += wv * vv.w;
    }
  }
  #pragma unroll
  for (int r = 0; r < 8; r++) {
    long long oidx = ((long long)(b * 512 + 256 + h * 32 + rg * 8 + r)) * 4096 + n0;
    float4 ov = {acc[r][0], acc[r][1], acc[r][2], acc[r][3]};
    *(float4*)(out + oidx) = ov;
  }
}

extern "C" void kernel_launch(void* const* d_in, const int* in_sizes, int n_in,
                              void* d_out, int out_size, void* d_ws, size_t ws_size,
                              hipStream_t stream) {
  const float* x    = (const float*)d_in[0];
  const float* modm = (const float*)d_in[1];
  const float* modb = (const float*)d_in[2];
  const float* Wq   = (const float*)d_in[3];
  const float* qkvb = (const float*)d_in[4];
  const float* peqh = (const float*)d_in[5];
  const float* peqw = (const float*)d_in[6];
  const float* pekh = (const float*)d_in[7];
  const float* pekw = (const float*)d_in[8];
  const float* pab  = (const float*)d_in[9];
  const float* pqb  = (const float*)d_in[10];
  float* out = (float*)d_out;

  // ws layout (67 MB total, <= 69.2 MB proven):
  //   [0, 0.75MB)    Wh/Wl u16[768][256] split-bf16 planes
  //   [1MB, 1.5MB)   logits f32[16][8][32][32] (atomic-accumulated, pre-scaled)
  //   [3MB, 67MB)    v fp32 [16][256][4096]
  unsigned short* Wh = (unsigned short*)d_ws;
  unsigned short* Wl = Wh + 768 * 256;
  float* logits = (float*)((char*)d_ws + (1 << 20));
  float* kv = (float*)((char*)d_ws + 3 * (1 << 20));

  hipMemsetAsync(logits, 0, 16 * 8 * 32 * 32 * sizeof(float), stream);
  k_wsplit<<<96, 256, 0, stream>>>(Wq, Wh, Wl);
  k_prep<<<4096, 256, 0, stream>>>(x, pab, pqb, out);
  k_qkl<<<4096, 256, 0, stream>>>(Wh, Wl, qkvb, peqh, peqw, pekh, pekw,
                                  modm, modb, out, logits);
  k_qkv<0><<<1024, 512, 32768, stream>>>(Wh, Wl, qkvb, peqh, peqw, pekh, pekw,
                                         modm, modb, out, kv, 512, 2);
  k_pv<<<2048, 256, 0, stream>>>(kv, logits, out);
}

// Round 7
// 317.633 us; speedup vs baseline: 1.5331x; 1.0945x over previous
//
#include <hip/hip_runtime.h>

typedef short bf16x8 __attribute__((ext_vector_type(8)));
typedef float f32x4 __attribute__((ext_vector_type(4)));

__device__ __forceinline__ float b2f(unsigned short u) {
  union { unsigned int i; float f; } v; v.i = ((unsigned int)u) << 16; return v.f;
}
__device__ __forceinline__ unsigned short f2b(float f) {
  unsigned int u = __float_as_uint(f);
  u += 0x7fffu + ((u >> 16) & 1u);
  return (unsigned short)(u >> 16);
}
__device__ __forceinline__ float silu_f(float s) { return s / (1.0f + __expf(-s)); }

// split fp32 -> (hi, lo) bf16
__device__ __forceinline__ void split2(float f, unsigned short& h, unsigned short& l) {
  h = f2b(f);
  l = f2b(f - b2f(h));
}

// async 16B/lane global->LDS. LDS dest = wave-uniform base + lane*16 (linear).
__device__ __forceinline__ void gload16(const unsigned short* g, unsigned short* l) {
  __builtin_amdgcn_global_load_lds(
      (const __attribute__((address_space(1))) unsigned int*)g,
      (__attribute__((address_space(3))) unsigned int*)l, 16, 0, 0);
}

// unpack 8 packed (hi | lo<<16) u32 -> hi/lo bf16x8 via v_perm (2 ops per pair)
__device__ __forceinline__ void unpack8(const unsigned* p, bf16x8& hi, bf16x8& lo) {
  uint4 a = *(const uint4*)p;
  uint4 b = *(const uint4*)(p + 4);
  unsigned u[8] = {a.x, a.y, a.z, a.w, b.x, b.y, b.z, b.w};
  unsigned hw[4], lw[4];
  #pragma unroll
  for (int j = 0; j < 4; j++) {
    hw[j] = __builtin_amdgcn_perm(u[2 * j + 1], u[2 * j], 0x05040100u);
    lw[j] = __builtin_amdgcn_perm(u[2 * j + 1], u[2 * j], 0x07060302u);
  }
  hi = *(bf16x8*)hw;
  lo = *(bf16x8*)lw;
}

// K0: split W fp32 -> Wh/Wl bf16 planes [768][256], once.
__global__ __launch_bounds__(256) void k_wsplit(
    const float* __restrict__ W, unsigned short* __restrict__ Wh,
    unsigned short* __restrict__ Wl) {
  int e = (blockIdx.x * 256 + threadIdx.x) * 8;  // 96 blocks * 256 * 8 = 768*256
  float4 a = *(const float4*)(W + e);
  float4 b = *(const float4*)(W + e + 4);
  float v[8] = {a.x, a.y, a.z, a.w, b.x, b.y, b.z, b.w};
  unsigned short h[8], l[8];
  #pragma unroll
  for (int j = 0; j < 8; j++) split2(v[j], h[j], l[j]);
  uint4 ph, pl;
  ph.x = h[0] | ((unsigned)h[1] << 16); ph.y = h[2] | ((unsigned)h[3] << 16);
  ph.z = h[4] | ((unsigned)h[5] << 16); ph.w = h[6] | ((unsigned)h[7] << 16);
  pl.x = l[0] | ((unsigned)l[1] << 16); pl.y = l[2] | ((unsigned)l[3] << 16);
  pl.z = l[4] | ((unsigned)l[5] << 16); pl.w = l[6] | ((unsigned)l[7] << 16);
  *(uint4*)(Wh + e) = ph;
  *(uint4*)(Wl + e) = pl;
}

// K1: fused prep+act:
//   x_preact = silu(x + pab) fp32 -> out[:,0:256]
//   T = x_preact + pqb, TRANSPOSED split planes -> out[:,256:512]
//     per batch: Th u16[4096][256] then Tl u16[4096][256]
__global__ __launch_bounds__(256) void k_prep(
    const float* __restrict__ x, const float* __restrict__ pab,
    const float* __restrict__ pqb, float* __restrict__ out) {
  __shared__ unsigned short th[64 * 64], tl[64 * 64];  // [n][c], sub-chunk swizzled
  int blk = blockIdx.x;
  int nb = blk & 63;
  int cb = (blk >> 6) & 3;
  int b = blk >> 8;
  int n0 = nb * 64, c0 = cb * 64;
  int t = threadIdx.x;
  int nn = (t & 15) * 4;
  #pragma unroll
  for (int p = 0; p < 2; p++) {
    int c = 2 * (p * 16 + (t >> 4));  // even
    float pa0 = pab[c0 + c], pq0 = pqb[c0 + c];
    float pa1 = pab[c0 + c + 1], pq1 = pqb[c0 + c + 1];
    float4 x0 = *(const float4*)(x + ((long long)(b * 256 + c0 + c)) * 4096 + n0 + nn);
    float4 x1 = *(const float4*)(x + ((long long)(b * 256 + c0 + c + 1)) * 4096 + n0 + nn);
    float s0[4] = {silu_f(x0.x + pa0), silu_f(x0.y + pa0),
                   silu_f(x0.z + pa0), silu_f(x0.w + pa0)};
    float s1[4] = {silu_f(x1.x + pa1), silu_f(x1.y + pa1),
                   silu_f(x1.z + pa1), silu_f(x1.w + pa1)};
    float4 sv0 = {s0[0], s0[1], s0[2], s0[3]};
    float4 sv1 = {s1[0], s1[1], s1[2], s1[3]};
    *(float4*)(out + ((long long)(b * 512 + c0 + c)) * 4096 + n0 + nn) = sv0;
    *(float4*)(out + ((long long)(b * 512 + c0 + c + 1)) * 4096 + n0 + nn) = sv1;
    float t0[4] = {s0[0] + pq0, s0[1] + pq0, s0[2] + pq0, s0[3] + pq0};
    float t1[4] = {s1[0] + pq1, s1[1] + pq1, s1[2] + pq1, s1[3] + pq1};
    #pragma unroll
    for (int j = 0; j < 4; j++) {
      int nr = nn + j;
      unsigned short h0, l0, h1, l1;
      split2(t0[j], h0, l0);
      split2(t1[j], h1, l1);
      int pcol = ((((c >> 3) ^ (nr & 7)) << 3) | (c & 7));
      *(unsigned int*)(th + nr * 64 + pcol) = (unsigned)h0 | ((unsigned)h1 << 16);
      *(unsigned int*)(tl + nr * 64 + pcol) = (unsigned)l0 | ((unsigned)l1 << 16);
    }
  }
  __syncthreads();
  unsigned short* Th = (unsigned short*)(out + ((long long)(b * 512 + 256)) * 4096);
  unsigned short* Tl = Th + 4096 * 256;
  #pragma unroll
  for (int q = 0; q < 2; q++) {
    int s = q * 256 + t;
    int n = s >> 3, sc = s & 7;
    int psc = sc ^ (n & 7);
    uint4 vh = *(const uint4*)(th + n * 64 + psc * 8);
    uint4 vl = *(const uint4*)(tl + n * 64 + psc * 8);
    *(uint4*)(Th + (long long)(n0 + n) * 256 + c0 + sc * 8) = vh;
    *(uint4*)(Tl + (long long)(n0 + n) * 256 + c0 + sc * 8) = vl;
  }
}

// K2: fused q/k/v GEMM + logits. One block = (b, head, ntile of 128 n).
// Main loop stages 26 x 1KB chunks (Ah q/k, Al q/k, Av v-hi, Bh, Bl) and runs
//   qk: 3-term split-bf16 (bit-identical to prior rounds)
//   v : 1-term hi-only (bit-identical to old k_qkv<0>)
// Epilogue: v -> kv fp32; q/k + bias + PE (+FiLM) packed -> swizzled qk LDS tile.
// Logits: q.k^T over this n-tile, cross-wave LDS reduce, atomicAdd into logits.
// LDS is a 32KB overlay: stg(26KB) | qk(32KB) | red(16KB) - phases separated
// by barriers. __launch_bounds__(256,3): VGPR cap ~170, no spill, 3 blocks/CU.
__global__ __launch_bounds__(256, 3) void k_qkl(
    const unsigned short* __restrict__ Wh, const unsigned short* __restrict__ Wl,
    const float* __restrict__ qkvb,
    const float* __restrict__ peqh, const float* __restrict__ peqw,
    const float* __restrict__ pekh, const float* __restrict__ pekw,
    const float* __restrict__ modm, const float* __restrict__ modb,
    const float* __restrict__ outT, float* __restrict__ kv,
    float* __restrict__ logits) {
  __shared__ __align__(16) unsigned char smem[32768];
  unsigned short* stg = (unsigned short*)smem;  // main loop: 26KB
  unsigned* qk = (unsigned*)smem;               // logits operand tile: 32KB
  float* red = (float*)smem;                    // cross-wave reduce: 16KB

  int bx = blockIdx.x;
  int ntile = bx & 31, h = (bx >> 5) & 7, b = bx >> 8;
  int n0 = ntile * 128;
  int t = threadIdx.x, lane = t & 63, w = t >> 6;
  int l15 = lane & 15, l4 = lane >> 4;

  const unsigned short* Th =
      (const unsigned short*)(outT + ((long long)(b * 512 + 256)) * 4096);
  const unsigned short* Tl = Th + 4096 * 256;

  // chunk c (16 rows x 32 u16 = 1KB): 0-3 Ah(q,q,k,k), 4-7 Al(q,q,k,k),
  // 8-9 Av(v,v), 10-17 Bh, 18-25 Bl. u16 LDS offsets: Ah 0, Al 2048, Av 4096,
  // Bh 5120, Bl 9216. Wave w stages c = w, w+4, ... (waves 0,1: 7; 2,3: 6).
  const unsigned short* csrc[7];
  unsigned short* cdst[7];
  int nc = (w < 2) ? 7 : 6;
  int lrow = lane >> 2;
  int lslot = ((lane & 3) ^ ((lane >> 3) & 3)) * 8;  // source-side swizzle
  #pragma unroll
  for (int i = 0; i < 7; i++) {
    int c = w + 4 * i;
    if (c > 25) c = 25;  // dummy (not issued)
    const unsigned short* plane;
    int rowb, ldsoff;
    if (c < 4) {
      plane = Wh; rowb = ((c & 2) ? 256 : 0) + h * 32 + (c & 1) * 16;
      ldsoff = c * 512;
    } else if (c < 8) {
      int s2 = c - 4;
      plane = Wl; rowb = ((s2 & 2) ? 256 : 0) + h * 32 + (s2 & 1) * 16;
      ldsoff = c * 512;
    } else if (c < 10) {
      plane = Wh; rowb = 512 + h * 32 + (c - 8) * 16;
      ldsoff = 4096 + (c - 8) * 512;
    } else if (c < 18) {
      plane = Th; rowb = n0 + (c - 10) * 16;
      ldsoff = 5120 + (c - 10) * 512;
    } else {
      plane = Tl; rowb = n0 + (c - 18) * 16;
      ldsoff = 9216 + (c - 18) * 512;
    }
    csrc[i] = plane + (long long)(rowb + lrow) * 256 + lslot;
    cdst[i] = stg + ldsoff;
  }

  int sw = (l4 ^ ((l15 >> 1) & 3)) << 3;  // read-side swizzle
  f32x4 z = {0.f, 0.f, 0.f, 0.f};
  f32x4 acc[4][2];   // q/k rows 0..63
  f32x4 accv[2][2];  // v rows 0..31
  #pragma unroll
  for (int i = 0; i < 4; i++)
    #pragma unroll
    for (int j = 0; j < 2; j++) acc[i][j] = z;
  #pragma unroll
  for (int i = 0; i < 2; i++)
    #pragma unroll
    for (int j = 0; j < 2; j++) accv[i][j] = z;

  for (int step = 0; step < 8; ++step) {
    int k0 = step * 32;
    #pragma unroll
    for (int i = 0; i < 7; i++)
      if (i < nc) gload16(csrc[i] + k0, cdst[i]);
    __syncthreads();
    // v phase first (av dies early -> lower peak VGPR)
    bf16x8 bh[2], av[2];
    #pragma unroll
    for (int j = 0; j < 2; j++)
      bh[j] = *(const bf16x8*)(stg + 5120 + (w * 32 + j * 16 + l15) * 32 + sw);
    #pragma unroll
    for (int i = 0; i < 2; i++)
      av[i] = *(const bf16x8*)(stg + 4096 + (i * 16 + l15) * 32 + sw);
    #pragma unroll
    for (int i = 0; i < 2; i++)
      #pragma unroll
      for (int j = 0; j < 2; j++)
        accv[i][j] = __builtin_amdgcn_mfma_f32_16x16x32_bf16(av[i], bh[j], accv[i][j], 0, 0, 0);
    __builtin_amdgcn_sched_barrier(0);
    // qk phase (3-term)
    bf16x8 ah[4], al[4], bl[2];
    #pragma unroll
    for (int i = 0; i < 4; i++) {
      int ro = (i * 16 + l15) * 32 + sw;
      ah[i] = *(const bf16x8*)(stg + ro);
      al[i] = *(const bf16x8*)(stg + 2048 + ro);
    }
    #pragma unroll
    for (int j = 0; j < 2; j++)
      bl[j] = *(const bf16x8*)(stg + 9216 + (w * 32 + j * 16 + l15) * 32 + sw);
    #pragma unroll
    for (int i = 0; i < 4; i++)
      #pragma unroll
      for (int j = 0; j < 2; j++) {
        acc[i][j] = __builtin_amdgcn_mfma_f32_16x16x32_bf16(ah[i], bh[j], acc[i][j], 0, 0, 0);
        acc[i][j] = __builtin_amdgcn_mfma_f32_16x16x32_bf16(ah[i], bl[j], acc[i][j], 0, 0, 0);
        acc[i][j] = __builtin_amdgcn_mfma_f32_16x16x32_bf16(al[i], bh[j], acc[i][j], 0, 0, 0);
      }
    __syncthreads();
  }

  // v epilogue: bias only -> kv fp32 (frees accv)
  int b256 = b * 256;
  #pragma unroll
  for (int i = 0; i < 2; i++) {
    #pragma unroll
    for (int r = 0; r < 4; r++) {
      int row = i * 16 + l4 * 4 + r;  // 0..31
      int cch = h * 32 + row;
      float bias = qkvb[512 + cch];
      #pragma unroll
      for (int j = 0; j < 2; j++) {
        int n = n0 + w * 32 + j * 16 + l15;
        kv[((long long)(b256 + cch)) * 4096 + n] = accv[i][j][r] + bias;
      }
    }
  }

  // q/k epilogue: bias + PE (+FiLM for q), pack, store to swizzled qk tile
  #pragma unroll
  for (int i = 0; i < 4; i++) {
    #pragma unroll
    for (int r = 0; r < 4; r++) {
      int row = i * 16 + l4 * 4 + r;  // 0..63; i<2 -> q, i>=2 -> k (wave-uniform)
      int cch = h * 32 + (row & 31);
      float bias = qkvb[(row & 32) ? (256 + cch) : cch];
      float mm = 0.f, mb = 0.f;
      if (row < 32) { mm = modm[b256 + cch]; mb = modb[b256 + cch]; }
      #pragma unroll
      for (int j = 0; j < 2; j++) {
        int nl = w * 32 + j * 16 + l15;
        int n = n0 + nl;
        int hh = n >> 6, ww = n & 63;
        float v = acc[i][j][r] + bias;
        if (row < 32) {
          v += peqh[cch * 64 + hh] + peqw[cch * 64 + ww];
          v = v * mm + mb;
        } else {
          v += pekh[cch * 64 + hh] + pekw[cch * 64 + ww];
        }
        unsigned short hi_, lo_;
        split2(v, hi_, lo_);
        int pch = (nl >> 3) ^ (row & 15);  // chunk swizzle (8 u32 = 32B chunks)
        qk[row * 128 + pch * 8 + (nl & 7)] = (unsigned)hi_ | ((unsigned)lo_ << 16);
      }
    }
  }
  __syncthreads();

  // logits partial: q(32 x 128n) . k(32 x 128n)^T; wave w covers n-slice w*32..
  f32x4 acc2[2][2] = {z, z, z, z};
  int chn = w * 4 + l4;
  bf16x8 qh[2], ql[2], kh[2], kl[2];
  #pragma unroll
  for (int i2 = 0; i2 < 2; i2++) {
    int row = i2 * 16 + l15;
    unpack8(qk + row * 128 + ((chn ^ l15) << 3), qh[i2], ql[i2]);
    unpack8(qk + (row + 32) * 128 + ((chn ^ l15) << 3), kh[i2], kl[i2]);
  }
  acc2[0][0] = __builtin_amdgcn_mfma_f32_16x16x32_bf16(qh[0], kh[0], acc2[0][0], 0, 0, 0);
  acc2[0][0] = __builtin_amdgcn_mfma_f32_16x16x32_bf16(qh[0], kl[0], acc2[0][0], 0, 0, 0);
  acc2[0][0] = __builtin_amdgcn_mfma_f32_16x16x32_bf16(ql[0], kh[0], acc2[0][0], 0, 0, 0);
  acc2[0][1] = __builtin_amdgcn_mfma_f32_16x16x32_bf16(qh[0], kh[1], acc2[0][1], 0, 0, 0);
  acc2[0][1] = __builtin_amdgcn_mfma_f32_16x16x32_bf16(qh[0], kl[1], acc2[0][1], 0, 0, 0);
  acc2[0][1] = __builtin_amdgcn_mfma_f32_16x16x32_bf16(ql[0], kh[1], acc2[0][1], 0, 0, 0);
  acc2[1][0] = __builtin_amdgcn_mfma_f32_16x16x32_bf16(qh[1], kh[0], acc2[1][0], 0, 0, 0);
  acc2[1][0] = __builtin_amdgcn_mfma_f32_16x16x32_bf16(qh[1], kl[0], acc2[1][0], 0, 0, 0);
  acc2[1][0] = __builtin_amdgcn_mfma_f32_16x16x32_bf16(ql[1], kh[0], acc2[1][0], 0, 0, 0);
  acc2[1][1] = __builtin_amdgcn_mfma_f32_16x16x32_bf16(qh[1], kh[1], acc2[1][1], 0, 0, 0);
  acc2[1][1] = __builtin_amdgcn_mfma_f32_16x16x32_bf16(qh[1], kl[1], acc2[1][1], 0, 0, 0);
  acc2[1][1] = __builtin_amdgcn_mfma_f32_16x16x32_bf16(ql[1], kh[1], acc2[1][1], 0, 0, 0);

  // red aliases qk: wait for ALL waves' qk reads before overwriting
  __syncthreads();
  #pragma unroll
  for (int i2 = 0; i2 < 2; i2++)
    #pragma unroll
    for (int j2 = 0; j2 < 2; j2++)
      #pragma unroll
      for (int r = 0; r < 4; r++)
        red[w * 1024 + (i2 * 16 + l4 * 4 + r) * 32 + j2 * 16 + l15] = acc2[i2][j2][r];
  __syncthreads();
  const float scale = 0.1767766952966369f;  // 1/sqrt(32)
  int bhid = b * 8 + h;
  #pragma unroll
  for (int i = 0; i < 4; i++) {
    int idx = i * 256 + t;
    float s = (red[idx] + red[1024 + idx] + red[2048 + idx] + red[3072 + idx]) * scale;
    atomicAdd(logits + (long long)bhid * 1024 + idx, s);
  }
}

// K3: softmax (logits already summed by atomics, already scaled) + weights @ v
__global__ __launch_bounds__(256) void k_pv(
    const float* __restrict__ kv,    // v
    const float* __restrict__ logits,
    float* __restrict__ out) {
  int bx = blockIdx.x;
  int ntile = bx & 15, bh = bx >> 4;
  int b = bh >> 3, h = bh & 7;
  int t = threadIdx.x;
  __shared__ float raw[32][33];   // [c][d], padded: serial reads conflict-free
  __shared__ float wsm[32][33];
  #pragma unroll
  for (int i = 0; i < 4; i++) {
    int idx = i * 256 + t;
    raw[idx >> 5][idx & 31] = logits[(long long)bh * 1024 + idx];
  }
  __syncthreads();
  if (t < 32) {
    float mx = -1e30f;
    for (int d = 0; d < 32; d++) mx = fmaxf(mx, raw[t][d]);
    float e[32]; float s = 0.f;
    for (int d = 0; d < 32; d++) { e[d] = __expf(raw[t][d] - mx); s += e[d]; }
    float inv = 1.0f / s;
    for (int d = 0; d < 32; d++) wsm[t][d] = e[d] * inv;
  }
  __syncthreads();
  int rg = t >> 6;          // wave-uniform -> wsm broadcast
  int nl = (t & 63) * 4;
  int n0 = ntile * 256 + nl;
  const float* vb = kv + ((long long)(b * 256 + h * 32)) * 4096 + n0;
  float acc[8][4];
  #pragma unroll
  for (int r = 0; r < 8; r++)
    #pragma unroll
    for (int i = 0; i < 4; i++) acc[r][i] = 0.f;
  for (int d = 0; d < 32; d++) {
    float4 vv = *(const float4*)(vb + (long long)d * 4096);
    #pragma unroll
    for (int r = 0; r < 8; r++) {
      float wv = wsm[rg * 8 + r][d];
      acc[r][0] += wv * vv.x; acc[r][1] += wv * vv.y;
      acc[r][2] += wv * vv.z; acc[r][3] += wv * vv.w;
    }
  }
  #pragma unroll
  for (int r = 0; r < 8; r++) {
    long long oidx = ((long long)(b * 512 + 256 + h * 32 + rg * 8 + r)) * 4096 + n0;
    float4 ov = {acc[r][0], acc[r][1], acc[r][2], acc[r][3]};
    *(float4*)(out + oidx) = ov;
  }
}

extern "C" void kernel_launch(void* const* d_in, const int* in_sizes, int n_in,
                              void* d_out, int out_size, void* d_ws, size_t ws_size,
                              hipStream_t stream) {
  const float* x    = (const float*)d_in[0];
  const float* modm = (const float*)d_in[1];
  const float* modb = (const float*)d_in[2];
  const float* Wq   = (const float*)d_in[3];
  const float* qkvb = (const float*)d_in[4];
  const float* peqh = (const float*)d_in[5];
  const float* peqw = (const float*)d_in[6];
  const float* pekh = (const float*)d_in[7];
  const float* pekw = (const float*)d_in[8];
  const float* pab  = (const float*)d_in[9];
  const float* pqb  = (const float*)d_in[10];
  float* out = (float*)d_out;

  // ws layout (67 MB total, <= 69.2 MB proven):
  //   [0, 0.75MB)    Wh/Wl u16[768][256] split-bf16 planes
  //   [1MB, 1.5MB)   logits f32[16][8][32][32] (atomic-accumulated, pre-scaled)
  //   [3MB, 67MB)    v fp32 [16][256][4096]
  unsigned short* Wh = (unsigned short*)d_ws;
  unsigned short* Wl = Wh + 768 * 256;
  float* logits = (float*)((char*)d_ws + (1 << 20));
  float* kv = (float*)((char*)d_ws + 3 * (1 << 20));

  hipMemsetAsync(logits, 0, 16 * 8 * 32 * 32 * sizeof(float), stream);
  k_wsplit<<<96, 256, 0, stream>>>(Wq, Wh, Wl);
  k_prep<<<4096, 256, 0, stream>>>(x, pab, pqb, out);
  k_qkl<<<4096, 256, 0, stream>>>(Wh, Wl, qkvb, peqh, peqw, pekh, pekw,
                                  modm, modb, out, kv, logits);
  k_pv<<<2048, 256, 0, stream>>>(kv, logits, out);
}